// Round 3
// baseline (712.936 us; speedup 1.0000x reference)
//
#include <hip/hip_runtime.h>
#include <hip/hip_bf16.h>

#define LL 512
#define CC 128
#define MM (LL*LL)   // 262144 positions

typedef __attribute__((ext_vector_type(8))) short bf16x8;
typedef __attribute__((ext_vector_type(4))) float f32x4;
using bf16 = __hip_bfloat16;

__device__ __forceinline__ float bf2f(bf16 h) { return __bfloat162float(h); }
__device__ __forceinline__ unsigned short f2bfbits(float f) {
    bf16 h = __float2bfloat16(f);
    return *reinterpret_cast<unsigned short*>(&h);
}
__device__ __forceinline__ void storeT(float* p, float v) { *p = v; }
__device__ __forceinline__ void storeT(bf16* p, float v) { *p = __float2bfloat16(v); }
__device__ __forceinline__ float loadT(const float* p) { return *p; }
__device__ __forceinline__ float loadT(const bf16* p) { return __bfloat162float(*p); }

// stage 8 consecutive elements into bf16 LDS (16B dst)
__device__ __forceinline__ void stage8(const float* src, bf16* dst) {
    float4 f0 = *(const float4*)(src);
    float4 f1 = *(const float4*)(src + 4);
    union { ushort4 v; unsigned short u[4]; } a, b;
    a.u[0] = f2bfbits(f0.x); a.u[1] = f2bfbits(f0.y);
    a.u[2] = f2bfbits(f0.z); a.u[3] = f2bfbits(f0.w);
    b.u[0] = f2bfbits(f1.x); b.u[1] = f2bfbits(f1.y);
    b.u[2] = f2bfbits(f1.z); b.u[3] = f2bfbits(f1.w);
    *(ushort4*)(dst)     = a.v;
    *(ushort4*)(dst + 4) = b.v;
}
__device__ __forceinline__ void stage8(const bf16* src, bf16* dst) {
    *(uint4*)dst = *(const uint4*)src;
}

// ---------------------------------------------------------------------------
// K0: convert six 128x128 fp32 weight matrices to bf16 in ws.
// grid (16, 6) x 256 threads, 4 elements/thread.
// ---------------------------------------------------------------------------
__global__ __launch_bounds__(256) void cvt_w_kernel(
    const float* __restrict__ s0, const float* __restrict__ s1,
    const float* __restrict__ s2, const float* __restrict__ s3,
    const float* __restrict__ s4, const float* __restrict__ s5,
    bf16* __restrict__ dst)
{
    const float* srcs[6] = {s0, s1, s2, s3, s4, s5};
    const float* s = srcs[blockIdx.y];
    bf16* d = dst + blockIdx.y * (CC * CC);
    int i = (blockIdx.x * 256 + threadIdx.x) * 4;
    float4 f = *(const float4*)(s + i);
    union { ushort4 v; unsigned short u[4]; } p;
    p.u[0] = f2bfbits(f.x); p.u[1] = f2bfbits(f.y);
    p.u[2] = f2bfbits(f.z); p.u[3] = f2bfbits(f.w);
    *(ushort4*)(d + i) = p.v;
}

// ---------------------------------------------------------------------------
// K1/K4: fused dual GEMM + sigmoid gate.
// out[m][n] = sigmoid(X[m]·W1[n] + b1[n]) * (X[m]·W2[n] + b2[n])
// X: [M x 128] InT row-major. W: bf16 [out=128][in=128] (pre-converted).
// TRANSPOSED=true  -> OUT[128][M] channel-major bf16 (feeds K2)
// TRANSPOSED=false -> OUT[M][128] row-major (final fp32 output)
// Tile: 64 rows x 128 cols, block=256 (4 waves, 16 rows each), K=128.
// ---------------------------------------------------------------------------
template<typename InT, typename OutT, bool TRANSPOSED>
__global__ __launch_bounds__(256) void proj_gate_kernel(
    const InT* __restrict__ X,
    const bf16* __restrict__ W1, const float* __restrict__ B1,
    const bf16* __restrict__ W2, const float* __restrict__ B2,
    OutT* __restrict__ OUT)
{
    __shared__ bf16 xs[64][136];          // +8 bf16 pad: 272B row stride
    const int t    = threadIdx.x;
    const int row0 = blockIdx.x * 64;

    // stage X tile: 64 rows x 128 cols = 1024 chunks of 8 elements
    #pragma unroll
    for (int it = 0; it < 4; ++it) {
        int chunk = it * 256 + t;
        int r = chunk >> 4, o = (chunk & 15) << 3;
        stage8(X + (size_t)(row0 + r) * CC + o, &xs[r][o]);
    }
    __syncthreads();

    const int wave = t >> 6, lane = t & 63;
    const int lrow = lane & 15, lq = lane >> 4;

    f32x4 acc1[8], acc2[8];
    const f32x4 z = {0.f, 0.f, 0.f, 0.f};
    #pragma unroll
    for (int i = 0; i < 8; ++i) { acc1[i] = z; acc2[i] = z; }

    #pragma unroll
    for (int k0 = 0; k0 < CC; k0 += 32) {
        // A frag: A[m=lrow][k = lq*8 + j]
        bf16x8 a = *(const bf16x8*)(&xs[wave * 16 + lrow][k0 + lq * 8]);
        #pragma unroll
        for (int nt = 0; nt < 8; ++nt) {
            const int n = nt * 16 + lrow;
            // B frag: B[k][n] = W[n][k] -> 8 contiguous k from W row n (L1/L2)
            bf16x8 w1 = *(const bf16x8*)(W1 + n * CC + k0 + lq * 8);
            bf16x8 w2 = *(const bf16x8*)(W2 + n * CC + k0 + lq * 8);
            acc1[nt] = __builtin_amdgcn_mfma_f32_16x16x32_bf16(a, w1, acc1[nt], 0, 0, 0);
            acc2[nt] = __builtin_amdgcn_mfma_f32_16x16x32_bf16(a, w2, acc2[nt], 0, 0, 0);
        }
    }

    // C/D layout: col = lane&15, row = (lane>>4)*4 + reg   [m89/m91 verified]
    #pragma unroll
    for (int nt = 0; nt < 8; ++nt) {
        const int n = nt * 16 + lrow;
        const float bias1 = B1[n];
        const float bias2 = B2[n];
        const int m0 = row0 + wave * 16 + lq * 4;
        if (TRANSPOSED) {
            union { ushort4 v; unsigned short u[4]; } pk;
            #pragma unroll
            for (int r = 0; r < 4; ++r) {
                float p1 = acc1[nt][r] + bias1;
                float p2 = acc2[nt][r] + bias2;
                float v  = p2 / (1.f + __expf(-p1));
                pk.u[r] = f2bfbits(v);
            }
            // 4 consecutive rows m at fixed channel n: one 8B store
            *(ushort4*)((bf16*)OUT + (size_t)n * MM + m0) = pk.v;
        } else {
            #pragma unroll
            for (int r = 0; r < 4; ++r) {
                float p1 = acc1[nt][r] + bias1;
                float p2 = acc2[nt][r] + bias2;
                float v  = p2 / (1.f + __expf(-p1));
                storeT(&OUT[(size_t)(m0 + r) * CC + n], v);
            }
        }
    }
}

// ---------------------------------------------------------------------------
// K2: per-channel batched GEMM  tri[c] = L_c (512x512) @ R_c^T (512x512)
// Lt/Rt: [128][512*512] bf16 (channel-major, k contiguous).
// tri: [128][512][512] TriT. Tile 128x128 per block, BK=32, 4 waves of 64x64.
// ---------------------------------------------------------------------------
template<typename TriT>
__global__ __launch_bounds__(256) void tri_mm_kernel(
    const bf16* __restrict__ Lt, const bf16* __restrict__ Rt,
    TriT* __restrict__ tri)
{
    __shared__ bf16 As[128][40];          // +8 bf16 pad: 80B row stride
    __shared__ bf16 Bs[128][40];
    const int c  = blockIdx.z;
    const int i0 = blockIdx.x * 128, j0 = blockIdx.y * 128;
    const bf16* Lb = Lt + (size_t)c * MM;
    const bf16* Rb = Rt + (size_t)c * MM;

    const int t    = threadIdx.x;
    const int wave = t >> 6, lane = t & 63;
    const int lrow = lane & 15, lq = lane >> 4;
    const int wi = (wave & 1) * 64, wj = (wave >> 1) * 64;

    f32x4 acc[4][4];
    const f32x4 z = {0.f, 0.f, 0.f, 0.f};
    #pragma unroll
    for (int mt = 0; mt < 4; ++mt)
        #pragma unroll
        for (int nt = 0; nt < 4; ++nt) acc[mt][nt] = z;

    for (int k0 = 0; k0 < LL; k0 += 32) {
        __syncthreads();                  // previous iter's frag reads done
        // stage A,B: 128 rows x 32 k each = 512 chunks of 16B per matrix
        #pragma unroll
        for (int it = 0; it < 2; ++it) {
            int chunk = it * 256 + t;
            int r = chunk >> 2, o = (chunk & 3) << 3;
            *(uint4*)(&As[r][o]) = *(const uint4*)(Lb + (size_t)(i0 + r) * LL + k0 + o);
            *(uint4*)(&Bs[r][o]) = *(const uint4*)(Rb + (size_t)(j0 + r) * LL + k0 + o);
        }
        __syncthreads();

        bf16x8 af[4], bfr[4];
        #pragma unroll
        for (int mt = 0; mt < 4; ++mt)
            af[mt] = *(const bf16x8*)(&As[wi + mt * 16 + lrow][lq * 8]);
        #pragma unroll
        for (int nt = 0; nt < 4; ++nt)
            bfr[nt] = *(const bf16x8*)(&Bs[wj + nt * 16 + lrow][lq * 8]);
        #pragma unroll
        for (int mt = 0; mt < 4; ++mt)
            #pragma unroll
            for (int nt = 0; nt < 4; ++nt)
                acc[mt][nt] = __builtin_amdgcn_mfma_f32_16x16x32_bf16(
                    af[mt], bfr[nt], acc[mt][nt], 0, 0, 0);
    }

    TriT* triC = tri + (size_t)c * MM;
    #pragma unroll
    for (int mt = 0; mt < 4; ++mt) {
        #pragma unroll
        for (int nt = 0; nt < 4; ++nt) {
            const int ib = i0 + wi + mt * 16 + lq * 4;
            const int j  = j0 + wj + nt * 16 + lrow;
            #pragma unroll
            for (int r = 0; r < 4; ++r)
                storeT(&triC[(size_t)(ib + r) * LL + j], acc[mt][nt][r]);
        }
    }
}

// ---------------------------------------------------------------------------
// K3: LayerNorm over channels. tri [128][M] -> ln [M][128] bf16.
// Block: 64 positions x 128 channels via padded LDS transpose.
// ---------------------------------------------------------------------------
template<typename TriT>
__global__ __launch_bounds__(256) void ln_kernel(
    const TriT* __restrict__ tri,
    const float* __restrict__ G, const float* __restrict__ Bt,
    bf16* __restrict__ OUT)
{
    __shared__ float s[128][65];          // +1 pad: fixed-p column reads conflict-free
    __shared__ float part[2][4][64];
    __shared__ float mu[64], rsd[64];
    const int t  = threadIdx.x;
    const int p0 = blockIdx.x * 64;
    const int pp = t & 63, cq = t >> 6;

    // gather: for each channel plane, 64 consecutive positions (coalesced)
    for (int c = cq; c < CC; c += 4)
        s[c][pp] = loadT(&tri[(size_t)c * MM + p0 + pp]);
    __syncthreads();

    // partial stats: thread (pp, cq) covers 32 channels
    float sum = 0.f, sq = 0.f;
    #pragma unroll 8
    for (int c = cq * 32; c < cq * 32 + 32; ++c) {
        float v = s[c][pp]; sum += v; sq += v * v;
    }
    part[0][cq][pp] = sum; part[1][cq][pp] = sq;
    __syncthreads();
    if (t < 64) {
        float S = part[0][0][t] + part[0][1][t] + part[0][2][t] + part[0][3][t];
        float Q = part[1][0][t] + part[1][1][t] + part[1][2][t] + part[1][3][t];
        float m = S * (1.f / 128.f);
        float var = Q * (1.f / 128.f) - m * m;
        mu[t] = m; rsd[t] = rsqrtf(var + 1e-5f);
    }
    __syncthreads();

    // write [p][c] bf16, fully coalesced 16B chunks
    #pragma unroll
    for (int it = 0; it < 4; ++it) {
        int chunk = it * 256 + t;
        int p = chunk >> 4, c8 = (chunk & 15) << 3;
        float m = mu[p], r = rsd[p];
        union { uint4 v; unsigned short u[8]; } pk;
        #pragma unroll
        for (int jj = 0; jj < 8; ++jj) {
            int c = c8 + jj;
            float v = (s[c][p] - m) * r * G[c] + Bt[c];
            pk.u[jj] = f2bfbits(v);
        }
        *(uint4*)(OUT + (size_t)(p0 + p) * CC + c8) = pk.v;
    }
}

// ---------------------------------------------------------------------------
extern "C" void kernel_launch(void* const* d_in, const int* in_sizes, int n_in,
                              void* d_out, int out_size, void* d_ws, size_t ws_size,
                              hipStream_t stream)
{
    // Reference dtypes are float32 for ALL inputs and the output.
    const float* x   = (const float*)d_in[0];
    const float* Wl1 = (const float*)d_in[1];
    const float* bl1 = (const float*)d_in[2];
    const float* Wl2 = (const float*)d_in[3];
    const float* bl2 = (const float*)d_in[4];
    const float* Wr1 = (const float*)d_in[5];
    const float* br1 = (const float*)d_in[6];
    const float* Wr2 = (const float*)d_in[7];
    const float* br2 = (const float*)d_in[8];
    const float* Wg  = (const float*)d_in[9];
    const float* bg  = (const float*)d_in[10];
    const float* Wo  = (const float*)d_in[11];
    const float* bo  = (const float*)d_in[12];
    const float* lng = (const float*)d_in[13];
    const float* lnb = (const float*)d_in[14];
    float* out = (float*)d_out;

    char* ws = (char*)d_ws;
    bf16* left_t  = (bf16*)(ws);                        // 64 MiB bf16 [128][M]
    bf16* right_t = (bf16*)(ws + (64ull << 20));        // 64 MiB bf16 [128][M]
    bf16* Wb      = (bf16*)(ws + (128ull << 20));       // 192 KiB: 6 bf16 weights
    void* tri     = (void*)(ws + (132ull << 20));       // 128 MiB fp32 / 64 MiB bf16
    bf16* ln_out  = (bf16*)(ws);                        // reuse left_t after K2

    const bool tri_fp32 = (ws_size >= (260ull << 20));

    bf16* Wbl1 = Wb + 0 * CC * CC;
    bf16* Wbl2 = Wb + 1 * CC * CC;
    bf16* Wbr1 = Wb + 2 * CC * CC;
    bf16* Wbr2 = Wb + 3 * CC * CC;
    bf16* Wbg  = Wb + 4 * CC * CC;
    bf16* Wbo  = Wb + 5 * CC * CC;

    dim3 blk(256);
    cvt_w_kernel<<<dim3(16, 6), blk, 0, stream>>>(Wl1, Wl2, Wr1, Wr2, Wg, Wo, Wb);
    proj_gate_kernel<float, bf16, true><<<dim3(MM / 64), blk, 0, stream>>>(
        x, Wbl1, bl1, Wbl2, bl2, left_t);
    proj_gate_kernel<float, bf16, true><<<dim3(MM / 64), blk, 0, stream>>>(
        x, Wbr1, br1, Wbr2, br2, right_t);
    if (tri_fp32) {
        tri_mm_kernel<float><<<dim3(4, 4, 128), blk, 0, stream>>>(left_t, right_t, (float*)tri);
        ln_kernel<float><<<dim3(MM / 64), blk, 0, stream>>>((const float*)tri, lng, lnb, ln_out);
    } else {
        tri_mm_kernel<bf16><<<dim3(4, 4, 128), blk, 0, stream>>>(left_t, right_t, (bf16*)tri);
        ln_kernel<bf16><<<dim3(MM / 64), blk, 0, stream>>>((const bf16*)tri, lng, lnb, ln_out);
    }
    proj_gate_kernel<bf16, float, false><<<dim3(MM / 64), blk, 0, stream>>>(
        ln_out, Wbg, bg, Wbo, bo, out);
}

// Round 4
// 489.102 us; speedup vs baseline: 1.4576x; 1.4576x over previous
//
#include <hip/hip_runtime.h>
#include <hip/hip_bf16.h>

#define LL 512
#define CC 128
#define MM (LL*LL)   // 262144 positions

typedef __attribute__((ext_vector_type(8))) short bf16x8;
typedef __attribute__((ext_vector_type(4))) float f32x4;
using bf16 = __hip_bfloat16;

__device__ __forceinline__ unsigned short f2bfbits(float f) {
    bf16 h = __float2bfloat16(f);
    return *reinterpret_cast<unsigned short*>(&h);
}
__device__ __forceinline__ void storeT(float* p, float v) { *p = v; }
__device__ __forceinline__ void storeT(bf16* p, float v) { *p = __float2bfloat16(v); }
__device__ __forceinline__ float loadT(const float* p) { return *p; }
__device__ __forceinline__ float loadT(const bf16* p) { return __bfloat162float(*p); }

// stage 8 consecutive elements into bf16 LDS (16B dst), with fp32->bf16 cvt
__device__ __forceinline__ void stage8(const float* src, bf16* dst) {
    float4 f0 = *(const float4*)(src);
    float4 f1 = *(const float4*)(src + 4);
    union { ushort4 v; unsigned short u[4]; } a, b;
    a.u[0] = f2bfbits(f0.x); a.u[1] = f2bfbits(f0.y);
    a.u[2] = f2bfbits(f0.z); a.u[3] = f2bfbits(f0.w);
    b.u[0] = f2bfbits(f1.x); b.u[1] = f2bfbits(f1.y);
    b.u[2] = f2bfbits(f1.z); b.u[3] = f2bfbits(f1.w);
    *(ushort4*)(dst)     = a.v;
    *(ushort4*)(dst + 4) = b.v;
}
__device__ __forceinline__ void stage8(const bf16* src, bf16* dst) {
    *(uint4*)dst = *(const uint4*)src;
}

// raw prefetch holders: load global early, convert/commit to LDS late
struct Raw8F {
    float4 a, b;
    __device__ __forceinline__ void load(const float* p) {
        a = *(const float4*)p; b = *(const float4*)(p + 4);
    }
    __device__ __forceinline__ void commit(bf16* d) const {
        union { ushort4 v; unsigned short u[4]; } x, y;
        x.u[0] = f2bfbits(a.x); x.u[1] = f2bfbits(a.y);
        x.u[2] = f2bfbits(a.z); x.u[3] = f2bfbits(a.w);
        y.u[0] = f2bfbits(b.x); y.u[1] = f2bfbits(b.y);
        y.u[2] = f2bfbits(b.z); y.u[3] = f2bfbits(b.w);
        *(ushort4*)(d)     = x.v;
        *(ushort4*)(d + 4) = y.v;
    }
};
struct Raw8B {
    uint4 a;
    __device__ __forceinline__ void load(const bf16* p) { a = *(const uint4*)p; }
    __device__ __forceinline__ void commit(bf16* d) const { *(uint4*)d = a; }
};
template<typename T> struct RawSel;
template<> struct RawSel<float> { using type = Raw8F; };
template<> struct RawSel<bf16>  { using type = Raw8B; };

// ---------------------------------------------------------------------------
// K0: convert six 128x128 fp32 weight matrices to bf16 in ws.
// ---------------------------------------------------------------------------
__global__ __launch_bounds__(256) void cvt_w_kernel(
    const float* __restrict__ s0, const float* __restrict__ s1,
    const float* __restrict__ s2, const float* __restrict__ s3,
    const float* __restrict__ s4, const float* __restrict__ s5,
    bf16* __restrict__ dst)
{
    const float* srcs[6] = {s0, s1, s2, s3, s4, s5};
    const float* s = srcs[blockIdx.y];
    bf16* d = dst + blockIdx.y * (CC * CC);
    int i = (blockIdx.x * 256 + threadIdx.x) * 4;
    float4 f = *(const float4*)(s + i);
    union { ushort4 v; unsigned short u[4]; } p;
    p.u[0] = f2bfbits(f.x); p.u[1] = f2bfbits(f.y);
    p.u[2] = f2bfbits(f.z); p.u[3] = f2bfbits(f.w);
    *(ushort4*)(d + i) = p.v;
}

// ---------------------------------------------------------------------------
// K1/K4: fused dual GEMM + sigmoid gate — R3 rewrite.
// out[m][n] = sigmoid(X[m]·W1[n] + b1[n]) * (X[m]·W2[n] + b2[n])
// Wave w owns cols [w*32, w*32+32) (nt_local 0..1); covers all 64 rows of a
// tile (mt 0..3). W fragments register-resident (16 frags = 64 VGPR/wave,
// loaded ONCE per block) — R3 fix for the L2-latency-bound inner loop
// (was: 64 global W loads per wave per tile -> MfmaUtil 4%, dur 165us).
// Block processes T=4 row-tiles of 64 with reg->LDS double-buffer prefetch.
// ---------------------------------------------------------------------------
template<typename InT, typename OutT, bool TRANSPOSED>
__global__ __launch_bounds__(256, 2) void proj_gate_kernel(
    const InT* __restrict__ X,
    const bf16* __restrict__ W1, const float* __restrict__ B1,
    const bf16* __restrict__ W2, const float* __restrict__ B2,
    OutT* __restrict__ OUT)
{
    __shared__ bf16 xs[2][64][136];       // +8 bf16 pad: 272B row stride
    const int t = threadIdx.x;
    const int wave = t >> 6, lane = t & 63;
    const int lrow = lane & 15, lq = lane >> 4;
    const int n0 = wave * 32 + lrow;      // this wave's first col (nl=0)

    // W fragments + biases, register-resident for the whole block
    bf16x8 wf1[2][4], wf2[2][4];          // [nt_local][k0/32]
    float bias1[2], bias2[2];
    #pragma unroll
    for (int nl = 0; nl < 2; ++nl) {
        const int n = n0 + nl * 16;
        bias1[nl] = B1[n]; bias2[nl] = B2[n];
        #pragma unroll
        for (int kk = 0; kk < 4; ++kk) {
            wf1[nl][kk] = *(const bf16x8*)(W1 + n * CC + kk * 32 + lq * 8);
            wf2[nl][kk] = *(const bf16x8*)(W2 + n * CC + kk * 32 + lq * 8);
        }
    }

    constexpr int T = 4;
    const size_t block_row0 = (size_t)blockIdx.x * (64 * T);

    // stage tile 0 directly
    #pragma unroll
    for (int it = 0; it < 4; ++it) {
        int chunk = it * 256 + t;
        int r = chunk >> 4, o = (chunk & 15) << 3;
        stage8(X + (block_row0 + r) * CC + o, &xs[0][r][o]);
    }

    using Raw = typename RawSel<InT>::type;

    #pragma unroll
    for (int tt = 0; tt < T; ++tt) {
        const size_t row0 = block_row0 + (size_t)tt * 64;
        const int cur = tt & 1;

        // issue next tile's global loads BEFORE the barrier: latency hides
        // under this tile's 64 MFMAs; waitcnt lands at commit() below.
        Raw pf[4];
        if (tt + 1 < T) {
            #pragma unroll
            for (int it = 0; it < 4; ++it) {
                int chunk = it * 256 + t;
                int r = chunk >> 4, o = (chunk & 15) << 3;
                pf[it].load(X + (row0 + 64 + r) * CC + o);
            }
        }
        __syncthreads();   // xs[cur] fully staged; xs[cur^1] reads (tt-1) done

        f32x4 acc1[2][4], acc2[2][4];     // [nt_local][mt]
        const f32x4 z = {0.f, 0.f, 0.f, 0.f};
        #pragma unroll
        for (int nl = 0; nl < 2; ++nl)
            #pragma unroll
            for (int mt = 0; mt < 4; ++mt) { acc1[nl][mt] = z; acc2[nl][mt] = z; }

        #pragma unroll
        for (int kk = 0; kk < 4; ++kk) {
            bf16x8 a[4];
            #pragma unroll
            for (int mt = 0; mt < 4; ++mt)
                a[mt] = *(const bf16x8*)(&xs[cur][mt * 16 + lrow][kk * 32 + lq * 8]);
            #pragma unroll
            for (int nl = 0; nl < 2; ++nl)
                #pragma unroll
                for (int mt = 0; mt < 4; ++mt) {
                    acc1[nl][mt] = __builtin_amdgcn_mfma_f32_16x16x32_bf16(
                        a[mt], wf1[nl][kk], acc1[nl][mt], 0, 0, 0);
                    acc2[nl][mt] = __builtin_amdgcn_mfma_f32_16x16x32_bf16(
                        a[mt], wf2[nl][kk], acc2[nl][mt], 0, 0, 0);
                }
        }

        // commit prefetched tile to the other LDS buffer (safe: its readers
        // finished before the barrier above; next readers wait on next barrier)
        if (tt + 1 < T) {
            #pragma unroll
            for (int it = 0; it < 4; ++it) {
                int chunk = it * 256 + t;
                int r = chunk >> 4, o = (chunk & 15) << 3;
                pf[it].commit(&xs[cur ^ 1][r][o]);
            }
        }

        // epilogue. C/D layout: col=lane&15 (-> n), row=(lane>>4)*4+reg (-> m)
        #pragma unroll
        for (int nl = 0; nl < 2; ++nl) {
            const int n = n0 + nl * 16;
            #pragma unroll
            for (int mt = 0; mt < 4; ++mt) {
                const size_t m0 = row0 + mt * 16 + lq * 4;
                if (TRANSPOSED) {
                    union { ushort4 v; unsigned short u[4]; } pk;
                    #pragma unroll
                    for (int r = 0; r < 4; ++r) {
                        float p1 = acc1[nl][mt][r] + bias1[nl];
                        float p2 = acc2[nl][mt][r] + bias2[nl];
                        pk.u[r] = f2bfbits(p2 / (1.f + __expf(-p1)));
                    }
                    *(ushort4*)((bf16*)OUT + (size_t)n * MM + m0) = pk.v;
                } else {
                    #pragma unroll
                    for (int r = 0; r < 4; ++r) {
                        float p1 = acc1[nl][mt][r] + bias1[nl];
                        float p2 = acc2[nl][mt][r] + bias2[nl];
                        storeT(&OUT[(m0 + r) * CC + n], p2 / (1.f + __expf(-p1)));
                    }
                }
            }
        }
    }
}

// ---------------------------------------------------------------------------
// K2: per-channel batched GEMM  tri[c] = L_c (512x512) @ R_c^T (512x512)
// ---------------------------------------------------------------------------
template<typename TriT>
__global__ __launch_bounds__(256) void tri_mm_kernel(
    const bf16* __restrict__ Lt, const bf16* __restrict__ Rt,
    TriT* __restrict__ tri)
{
    __shared__ bf16 As[128][40];          // +8 bf16 pad: 80B row stride
    __shared__ bf16 Bs[128][40];
    const int c  = blockIdx.z;
    const int i0 = blockIdx.x * 128, j0 = blockIdx.y * 128;
    const bf16* Lb = Lt + (size_t)c * MM;
    const bf16* Rb = Rt + (size_t)c * MM;

    const int t    = threadIdx.x;
    const int wave = t >> 6, lane = t & 63;
    const int lrow = lane & 15, lq = lane >> 4;
    const int wi = (wave & 1) * 64, wj = (wave >> 1) * 64;

    f32x4 acc[4][4];
    const f32x4 z = {0.f, 0.f, 0.f, 0.f};
    #pragma unroll
    for (int mt = 0; mt < 4; ++mt)
        #pragma unroll
        for (int nt = 0; nt < 4; ++nt) acc[mt][nt] = z;

    for (int k0 = 0; k0 < LL; k0 += 32) {
        __syncthreads();
        #pragma unroll
        for (int it = 0; it < 2; ++it) {
            int chunk = it * 256 + t;
            int r = chunk >> 2, o = (chunk & 3) << 3;
            *(uint4*)(&As[r][o]) = *(const uint4*)(Lb + (size_t)(i0 + r) * LL + k0 + o);
            *(uint4*)(&Bs[r][o]) = *(const uint4*)(Rb + (size_t)(j0 + r) * LL + k0 + o);
        }
        __syncthreads();

        bf16x8 af[4], bfr[4];
        #pragma unroll
        for (int mt = 0; mt < 4; ++mt)
            af[mt] = *(const bf16x8*)(&As[wi + mt * 16 + lrow][lq * 8]);
        #pragma unroll
        for (int nt = 0; nt < 4; ++nt)
            bfr[nt] = *(const bf16x8*)(&Bs[wj + nt * 16 + lrow][lq * 8]);
        #pragma unroll
        for (int mt = 0; mt < 4; ++mt)
            #pragma unroll
            for (int nt = 0; nt < 4; ++nt)
                acc[mt][nt] = __builtin_amdgcn_mfma_f32_16x16x32_bf16(
                    af[mt], bfr[nt], acc[mt][nt], 0, 0, 0);
    }

    TriT* triC = tri + (size_t)c * MM;
    #pragma unroll
    for (int mt = 0; mt < 4; ++mt) {
        #pragma unroll
        for (int nt = 0; nt < 4; ++nt) {
            const int ib = i0 + wi + mt * 16 + lq * 4;
            const int j  = j0 + wj + nt * 16 + lrow;
            #pragma unroll
            for (int r = 0; r < 4; ++r)
                storeT(&triC[(size_t)(ib + r) * LL + j], acc[mt][nt][r]);
        }
    }
}

// ---------------------------------------------------------------------------
// K3: LayerNorm over channels. tri [128][M] -> ln [M][128] bf16.
// ---------------------------------------------------------------------------
template<typename TriT>
__global__ __launch_bounds__(256) void ln_kernel(
    const TriT* __restrict__ tri,
    const float* __restrict__ G, const float* __restrict__ Bt,
    bf16* __restrict__ OUT)
{
    __shared__ float s[128][65];
    __shared__ float part[2][4][64];
    __shared__ float mu[64], rsd[64];
    const int t  = threadIdx.x;
    const int p0 = blockIdx.x * 64;
    const int pp = t & 63, cq = t >> 6;

    for (int c = cq; c < CC; c += 4)
        s[c][pp] = loadT(&tri[(size_t)c * MM + p0 + pp]);
    __syncthreads();

    float sum = 0.f, sq = 0.f;
    #pragma unroll 8
    for (int c = cq * 32; c < cq * 32 + 32; ++c) {
        float v = s[c][pp]; sum += v; sq += v * v;
    }
    part[0][cq][pp] = sum; part[1][cq][pp] = sq;
    __syncthreads();
    if (t < 64) {
        float S = part[0][0][t] + part[0][1][t] + part[0][2][t] + part[0][3][t];
        float Q = part[1][0][t] + part[1][1][t] + part[1][2][t] + part[1][3][t];
        float m = S * (1.f / 128.f);
        float var = Q * (1.f / 128.f) - m * m;
        mu[t] = m; rsd[t] = rsqrtf(var + 1e-5f);
    }
    __syncthreads();

    #pragma unroll
    for (int it = 0; it < 4; ++it) {
        int chunk = it * 256 + t;
        int p = chunk >> 4, c8 = (chunk & 15) << 3;
        float m = mu[p], r = rsd[p];
        union { uint4 v; unsigned short u[8]; } pk;
        #pragma unroll
        for (int jj = 0; jj < 8; ++jj) {
            int c = c8 + jj;
            float v = (s[c][p] - m) * r * G[c] + Bt[c];
            pk.u[jj] = f2bfbits(v);
        }
        *(uint4*)(OUT + (size_t)(p0 + p) * CC + c8) = pk.v;
    }
}

// ---------------------------------------------------------------------------
extern "C" void kernel_launch(void* const* d_in, const int* in_sizes, int n_in,
                              void* d_out, int out_size, void* d_ws, size_t ws_size,
                              hipStream_t stream)
{
    const float* x   = (const float*)d_in[0];
    const float* Wl1 = (const float*)d_in[1];
    const float* bl1 = (const float*)d_in[2];
    const float* Wl2 = (const float*)d_in[3];
    const float* bl2 = (const float*)d_in[4];
    const float* Wr1 = (const float*)d_in[5];
    const float* br1 = (const float*)d_in[6];
    const float* Wr2 = (const float*)d_in[7];
    const float* br2 = (const float*)d_in[8];
    const float* Wg  = (const float*)d_in[9];
    const float* bg  = (const float*)d_in[10];
    const float* Wo  = (const float*)d_in[11];
    const float* bo  = (const float*)d_in[12];
    const float* lng = (const float*)d_in[13];
    const float* lnb = (const float*)d_in[14];
    float* out = (float*)d_out;

    char* ws = (char*)d_ws;
    bf16* left_t  = (bf16*)(ws);                        // 64 MiB bf16 [128][M]
    bf16* right_t = (bf16*)(ws + (64ull << 20));        // 64 MiB bf16 [128][M]
    bf16* Wb      = (bf16*)(ws + (128ull << 20));       // 192 KiB: 6 bf16 weights
    void* tri     = (void*)(ws + (132ull << 20));       // 128 MiB fp32 / 64 MiB bf16
    bf16* ln_out  = (bf16*)(ws);                        // reuse left_t after K2

    const bool tri_fp32 = (ws_size >= (260ull << 20));

    bf16* Wbl1 = Wb + 0 * CC * CC;
    bf16* Wbl2 = Wb + 1 * CC * CC;
    bf16* Wbr1 = Wb + 2 * CC * CC;
    bf16* Wbr2 = Wb + 3 * CC * CC;
    bf16* Wbg  = Wb + 4 * CC * CC;
    bf16* Wbo  = Wb + 5 * CC * CC;

    dim3 blk(256);
    cvt_w_kernel<<<dim3(16, 6), blk, 0, stream>>>(Wl1, Wl2, Wr1, Wr2, Wg, Wo, Wb);
    proj_gate_kernel<float, bf16, true><<<dim3(MM / 256), blk, 0, stream>>>(
        x, Wbl1, bl1, Wbl2, bl2, left_t);
    proj_gate_kernel<float, bf16, true><<<dim3(MM / 256), blk, 0, stream>>>(
        x, Wbr1, br1, Wbr2, br2, right_t);
    if (tri_fp32) {
        tri_mm_kernel<float><<<dim3(4, 4, 128), blk, 0, stream>>>(left_t, right_t, (float*)tri);
        ln_kernel<float><<<dim3(MM / 64), blk, 0, stream>>>((const float*)tri, lng, lnb, ln_out);
    } else {
        tri_mm_kernel<bf16><<<dim3(4, 4, 128), blk, 0, stream>>>(left_t, right_t, (bf16*)tri);
        ln_kernel<bf16><<<dim3(MM / 64), blk, 0, stream>>>((const bf16*)tri, lng, lnb, ln_out);
    }
    proj_gate_kernel<bf16, float, false><<<dim3(MM / 256), blk, 0, stream>>>(
        ln_out, Wbg, bg, Wbo, bo, out);
}